// Round 2
// baseline (270.893 us; speedup 1.0000x reference)
//
#include <hip/hip_runtime.h>
#include <math.h>

#define DEV __device__ __forceinline__

DEV float fast_rcp(float x) { return __builtin_amdgcn_rcpf(x); }

// Abramowitz-Stegun 4.4.45: |err| <= 6.8e-5 rad on [-1,1].
DEV float fast_acos(float x) {
    float ax = fabsf(x);
    float p = fmaf(ax, -0.0187293f, 0.0742610f);
    p = fmaf(ax, p, -0.2121144f);
    p = fmaf(ax, p, 1.5707288f);
    float r = sqrtf(1.0f - ax) * p;
    return (x < 0.0f) ? (3.14159265358979f - r) : r;
}

// se3 exponential; K^2 = phi phi^T - |phi|^2 I identity avoids matmuls.
DEV void se3_exp(float tau0, float tau1, float tau2,
                 float x, float y, float z,
                 float R[9], float t[3]) {
    float th2 = x*x + y*y + z*z;
    float th  = sqrtf(th2);
    bool small = th < 1e-4f;
    float ts  = small ? 1.0f : th;
    float s   = __sinf(ts);
    float c   = __cosf(ts);
    float inv = fast_rcp(ts);
    float A = small ? (1.0f - th2 * (1.0f/6.0f))      : s * inv;
    float B = small ? (0.5f - th2 * (1.0f/24.0f))     : (1.0f - c) * inv * inv;
    float C = small ? (1.0f/6.0f - th2*(1.0f/120.0f)) : (ts - s) * inv * inv * inv;

    float Bxy = B*x*y, Bxz = B*x*z, Byz = B*y*z;
    R[0] = 1.0f - B*(y*y + z*z);
    R[1] = Bxy - A*z;
    R[2] = Bxz + A*y;
    R[3] = Bxy + A*z;
    R[4] = 1.0f - B*(x*x + z*z);
    R[5] = Byz - A*x;
    R[6] = Bxz - A*y;
    R[7] = Byz + A*x;
    R[8] = 1.0f - B*(x*x + y*y);

    float Cxy = C*x*y, Cxz = C*x*z, Cyz = C*y*z;
    float V0 = 1.0f - C*(y*y + z*z);
    float V1 = Cxy - B*z;
    float V2 = Cxz + B*y;
    float V3 = Cxy + B*z;
    float V4 = 1.0f - C*(x*x + z*z);
    float V5 = Cyz - B*x;
    float V6 = Cxz - B*y;
    float V7 = Cyz + B*x;
    float V8 = 1.0f - C*(x*x + y*y);
    t[0] = V0*tau0 + V1*tau1 + V2*tau2;
    t[1] = V3*tau0 + V4*tau1 + V5*tau2;
    t[2] = V6*tau0 + V7*tau1 + V8*tau2;
}

// One block per trajectory (128 threads).
// Phase 1: thread t builds fwd_t = exp(v_t h)∘exp(x_t), bwd_t = exp(v_t h)^-1∘exp(x_t)
//          (2 exps instead of 4; the -h exp is the exact inverse of the +h exp).
// Phase 2: thread t<127 composes fwd_t ∘ inv(bwd_{t+1}), takes the SE(3) log, loss.
// LDS rows stride 13 (odd): lanes 32 apart alias the same bank -> free 2-way.
__global__ __launch_bounds__(128)
void kin_kernel(const float* __restrict__ traj, const int* __restrict__ kidx,
                const float* __restrict__ tw, const float* __restrict__ kw,
                float* __restrict__ partial, unsigned int* __restrict__ counter,
                float* __restrict__ out, int nblocks) {
    __shared__ float fS[128 * 13];   // fwd: R(9) + t(3)
    __shared__ float bS[128 * 13];   // bwd: R(9) + t(3)
    __shared__ float wsum[2];
    __shared__ int last;
    const int b   = blockIdx.x;
    const int tid = threadIdx.x;

    const float* row = traj + (size_t)b * 1536 + tid * 12;
    float4 v0 = *(const float4*)(row + 0);
    float4 v1 = *(const float4*)(row + 4);
    float4 v2 = *(const float4*)(row + 8);

    float Rp[9], tp[3], Rv[9], tv[3];
    se3_exp(v0.x, v0.y, v0.z, v0.w, v1.x, v1.y, Rp, tp);
    const float h = 0.05f;   // DT/2
    se3_exp(v1.z*h, v1.w*h, v2.x*h, v2.y*h, v2.z*h, v2.w*h, Rv, tv);

    float* f = &fS[tid * 13];
    float* g = &bS[tid * 13];
    #pragma unroll
    for (int i = 0; i < 3; i++) {
        #pragma unroll
        for (int j = 0; j < 3; j++) {
            // fwd: Rv * Rp      bwd: Rv^T * Rp
            f[i*3+j] = Rv[i*3+0]*Rp[0*3+j] + Rv[i*3+1]*Rp[1*3+j] + Rv[i*3+2]*Rp[2*3+j];
            g[i*3+j] = Rv[0*3+i]*Rp[0*3+j] + Rv[1*3+i]*Rp[1*3+j] + Rv[2*3+i]*Rp[2*3+j];
        }
    }
    float d0 = tp[0] - tv[0], d1 = tp[1] - tv[1], d2 = tp[2] - tv[2];
    #pragma unroll
    for (int i = 0; i < 3; i++) {
        f[9+i] = Rv[i*3+0]*tp[0] + Rv[i*3+1]*tp[1] + Rv[i*3+2]*tp[2] + tv[i];
        g[9+i] = Rv[0*3+i]*d0 + Rv[1*3+i]*d1 + Rv[2*3+i]*d2;
    }
    __syncthreads();

    float term = 0.0f;
    if (tid < 127) {
        const float* F = &fS[tid * 13];
        const float* B = &bS[(tid + 1) * 13];
        // Rd = Rf * Rb^T ; td = tf - Rd * tb
        float Rd[9];
        #pragma unroll
        for (int i = 0; i < 3; i++)
            #pragma unroll
            for (int j = 0; j < 3; j++)
                Rd[i*3+j] = F[i*3+0]*B[j*3+0] + F[i*3+1]*B[j*3+1] + F[i*3+2]*B[j*3+2];
        float td0 = F[9]  - (Rd[0]*B[9] + Rd[1]*B[10] + Rd[2]*B[11]);
        float td1 = F[10] - (Rd[3]*B[9] + Rd[4]*B[10] + Rd[5]*B[11]);
        float td2 = F[11] - (Rd[6]*B[9] + Rd[7]*B[10] + Rd[8]*B[11]);

        // so3_log: clamp guarantees th >= 4.47e-4, so the `small` branches of
        // the reference are statically dead; sin(th)=sqrt(1-c^2), cos(th)=c.
        float tr = Rd[0] + Rd[4] + Rd[8];
        float c  = fminf(fmaxf((tr - 1.0f) * 0.5f, -1.0f + 1e-7f), 1.0f - 1e-7f);
        float th = fast_acos(c);
        float sn = sqrtf(fmaxf(1.0f - c*c, 1e-20f));
        float coef = th * fast_rcp(2.0f * sn);
        float px = coef * (Rd[7] - Rd[5]);
        float py = coef * (Rd[2] - Rd[6]);
        float pz = coef * (Rd[3] - Rd[1]);

        // se3_log: Vinv = I - 0.5 K + D (pp^T - |p|^2 I)
        float D = (1.0f - th*sn*fast_rcp(2.0f*(1.0f - c))) * fast_rcp(th*th);
        float Dxy = D*px*py, Dxz = D*px*pz, Dyz = D*py*pz;
        float Vi0 = 1.0f - D*(py*py + pz*pz);
        float Vi1 = Dxy + 0.5f*pz;
        float Vi2 = Dxz - 0.5f*py;
        float Vi3 = Dxy - 0.5f*pz;
        float Vi4 = 1.0f - D*(px*px + pz*pz);
        float Vi5 = Dyz + 0.5f*px;
        float Vi6 = Dxz + 0.5f*py;
        float Vi7 = Dyz - 0.5f*px;
        float Vi8 = 1.0f - D*(px*px + py*py);
        float ux = Vi0*td0 + Vi1*td1 + Vi2*td2;
        float uy = Vi3*td0 + Vi4*td1 + Vi5*td2;
        float uz = Vi6*td0 + Vi7*td1 + Vi8*td2;

        float loss = ux*ux + uy*uy + uz*uz + px*px + py*py + pz*pz;
        term = loss * tw[tid];
    }

    // block reduction (2 waves)
    float v = term;
    #pragma unroll
    for (int off = 32; off; off >>= 1) v += __shfl_down(v, off, 64);
    if ((tid & 63) == 0) wsum[tid >> 6] = v;
    __syncthreads();
    if (tid == 0) {
        partial[b] = (wsum[0] + wsum[1]) * kw[kidx[b]];
        __threadfence();                       // release partial before counter
        unsigned old = atomicAdd(counter, 1u);
        last = (old == (unsigned)(nblocks - 1)) ? 1 : 0;
    }
    __syncthreads();
    if (last) {                                // block-uniform
        __threadfence();                       // acquire side
        float s = 0.0f;
        for (int i = tid; i < nblocks; i += 128) s += partial[i];
        #pragma unroll
        for (int off = 32; off; off >>= 1) s += __shfl_down(s, off, 64);
        if ((tid & 63) == 0) wsum[tid >> 6] = s;
        __syncthreads();
        if (tid == 0)
            out[0] = (wsum[0] + wsum[1]) * fast_rcp(127.0f * (float)nblocks);
    }
}

extern "C" void kernel_launch(void* const* d_in, const int* in_sizes, int n_in,
                              void* d_out, int out_size, void* d_ws, size_t ws_size,
                              hipStream_t stream) {
    const float* traj = (const float*)d_in[0];
    const int*   k    = (const int*)d_in[1];
    const float* tw   = (const float*)d_in[2];
    const float* kw   = (const float*)d_in[3];
    float* out = (float*)d_out;
    unsigned int* counter = (unsigned int*)d_ws;
    float* partial = (float*)((char*)d_ws + 256);
    const int B = in_sizes[1];  // 8192 trajectories

    hipMemsetAsync(counter, 0, sizeof(unsigned int), stream);
    kin_kernel<<<B, 128, 0, stream>>>(traj, k, tw, kw, partial, counter, out, B);
}

// Round 3
// 101.890 us; speedup vs baseline: 2.6587x; 2.6587x over previous
//
#include <hip/hip_runtime.h>
#include <math.h>

#define DEV __device__ __forceinline__

DEV float fast_rcp(float x) { return __builtin_amdgcn_rcpf(x); }

// Abramowitz-Stegun 4.4.45: |err| <= 6.8e-5 rad on [-1,1].
DEV float fast_acos(float x) {
    float ax = fabsf(x);
    float p = fmaf(ax, -0.0187293f, 0.0742610f);
    p = fmaf(ax, p, -0.2121144f);
    p = fmaf(ax, p, 1.5707288f);
    float r = sqrtf(1.0f - ax) * p;
    return (x < 0.0f) ? (3.14159265358979f - r) : r;
}

// se3 exponential; K^2 = phi phi^T - |phi|^2 I identity avoids matmuls.
DEV void se3_exp(float tau0, float tau1, float tau2,
                 float x, float y, float z,
                 float R[9], float t[3]) {
    float th2 = x*x + y*y + z*z;
    float th  = sqrtf(th2);
    bool small = th < 1e-4f;
    float ts  = small ? 1.0f : th;
    float s   = __sinf(ts);
    float c   = __cosf(ts);
    float inv = fast_rcp(ts);
    float A = small ? (1.0f - th2 * (1.0f/6.0f))      : s * inv;
    float B = small ? (0.5f - th2 * (1.0f/24.0f))     : (1.0f - c) * inv * inv;
    float C = small ? (1.0f/6.0f - th2*(1.0f/120.0f)) : (ts - s) * inv * inv * inv;

    float Bxy = B*x*y, Bxz = B*x*z, Byz = B*y*z;
    R[0] = 1.0f - B*(y*y + z*z);
    R[1] = Bxy - A*z;
    R[2] = Bxz + A*y;
    R[3] = Bxy + A*z;
    R[4] = 1.0f - B*(x*x + z*z);
    R[5] = Byz - A*x;
    R[6] = Bxz - A*y;
    R[7] = Byz + A*x;
    R[8] = 1.0f - B*(x*x + y*y);

    float Cxy = C*x*y, Cxz = C*x*z, Cyz = C*y*z;
    float V0 = 1.0f - C*(y*y + z*z);
    float V1 = Cxy - B*z;
    float V2 = Cxz + B*y;
    float V3 = Cxy + B*z;
    float V4 = 1.0f - C*(x*x + z*z);
    float V5 = Cyz - B*x;
    float V6 = Cxz - B*y;
    float V7 = Cyz + B*x;
    float V8 = 1.0f - C*(x*x + y*y);
    t[0] = V0*tau0 + V1*tau1 + V2*tau2;
    t[1] = V3*tau0 + V4*tau1 + V5*tau2;
    t[2] = V6*tau0 + V7*tau1 + V8*tau2;
}

// One block per trajectory (128 threads).
// Thread t builds Hp=exp(pose_t), Hv=exp(vel_t*h); fwd_t = Hv∘Hp kept in
// REGISTERS, bwd_t = Hv^-1∘Hp written to LDS (the only cross-thread value;
// exp(-h v) = exp(h v)^-1, so no extra exps). Then thread t<127 composes
// fwd_t ∘ inv(bwd_{t+1}) and takes the SE(3) log.
// LDS rows stride 13 (odd): lanes 32 apart alias the same bank -> free 2-way.
__global__ __launch_bounds__(128)
void kin_kernel(const float* __restrict__ traj, const int* __restrict__ kidx,
                const float* __restrict__ tw, const float* __restrict__ kw,
                float* __restrict__ partial) {
    __shared__ float bS[128 * 13];   // bwd: R(9) + t(3)
    __shared__ float wsum[2];
    const int b   = blockIdx.x;
    const int tid = threadIdx.x;

    const float* row = traj + (size_t)b * 1536 + tid * 12;
    float4 v0 = *(const float4*)(row + 0);
    float4 v1 = *(const float4*)(row + 4);
    float4 v2 = *(const float4*)(row + 8);
    float tweight = (tid < 127) ? tw[tid] : 0.0f;

    float Rp[9], tp[3], Rv[9], tv[3];
    se3_exp(v0.x, v0.y, v0.z, v0.w, v1.x, v1.y, Rp, tp);
    const float h = 0.05f;   // DT/2
    se3_exp(v1.z*h, v1.w*h, v2.x*h, v2.y*h, v2.z*h, v2.w*h, Rv, tv);

    // fwd (registers): Rf = Rv*Rp, tf = Rv*tp + tv
    float F[12];
    float* g = &bS[tid * 13];
    #pragma unroll
    for (int i = 0; i < 3; i++) {
        #pragma unroll
        for (int j = 0; j < 3; j++) {
            F[i*3+j]  = Rv[i*3+0]*Rp[0*3+j] + Rv[i*3+1]*Rp[1*3+j] + Rv[i*3+2]*Rp[2*3+j];
            g[i*3+j]  = Rv[0*3+i]*Rp[0*3+j] + Rv[1*3+i]*Rp[1*3+j] + Rv[2*3+i]*Rp[2*3+j];
        }
    }
    float d0 = tp[0] - tv[0], d1 = tp[1] - tv[1], d2 = tp[2] - tv[2];
    #pragma unroll
    for (int i = 0; i < 3; i++) {
        F[9+i] = Rv[i*3+0]*tp[0] + Rv[i*3+1]*tp[1] + Rv[i*3+2]*tp[2] + tv[i];
        g[9+i] = Rv[0*3+i]*d0 + Rv[1*3+i]*d1 + Rv[2*3+i]*d2;
    }
    __syncthreads();

    float term = 0.0f;
    if (tid < 127) {
        const float* B = &bS[(tid + 1) * 13];
        // Rd = Rf * Rb^T ; td = tf - Rd * tb
        float Rd[9];
        #pragma unroll
        for (int i = 0; i < 3; i++)
            #pragma unroll
            for (int j = 0; j < 3; j++)
                Rd[i*3+j] = F[i*3+0]*B[j*3+0] + F[i*3+1]*B[j*3+1] + F[i*3+2]*B[j*3+2];
        float td0 = F[9]  - (Rd[0]*B[9] + Rd[1]*B[10] + Rd[2]*B[11]);
        float td1 = F[10] - (Rd[3]*B[9] + Rd[4]*B[10] + Rd[5]*B[11]);
        float td2 = F[11] - (Rd[6]*B[9] + Rd[7]*B[10] + Rd[8]*B[11]);

        // so3_log: clamp guarantees th >= 4.47e-4 -> `small` branches dead;
        // sin(th)=sqrt(1-c^2), cos(th)=c -> no sin/cos needed.
        float tr = Rd[0] + Rd[4] + Rd[8];
        float c  = fminf(fmaxf((tr - 1.0f) * 0.5f, -1.0f + 1e-7f), 1.0f - 1e-7f);
        float th = fast_acos(c);
        float sn = sqrtf(fmaxf(1.0f - c*c, 1e-20f));
        float coef = th * fast_rcp(2.0f * sn);
        float px = coef * (Rd[7] - Rd[5]);
        float py = coef * (Rd[2] - Rd[6]);
        float pz = coef * (Rd[3] - Rd[1]);

        // se3_log: Vinv = I - 0.5 K + D (pp^T - |p|^2 I)
        float D = (1.0f - th*sn*fast_rcp(2.0f*(1.0f - c))) * fast_rcp(th*th);
        float Dxy = D*px*py, Dxz = D*px*pz, Dyz = D*py*pz;
        float Vi0 = 1.0f - D*(py*py + pz*pz);
        float Vi1 = Dxy + 0.5f*pz;
        float Vi2 = Dxz - 0.5f*py;
        float Vi3 = Dxy - 0.5f*pz;
        float Vi4 = 1.0f - D*(px*px + pz*pz);
        float Vi5 = Dyz + 0.5f*px;
        float Vi6 = Dxz + 0.5f*py;
        float Vi7 = Dyz - 0.5f*px;
        float Vi8 = 1.0f - D*(px*px + py*py);
        float ux = Vi0*td0 + Vi1*td1 + Vi2*td2;
        float uy = Vi3*td0 + Vi4*td1 + Vi5*td2;
        float uz = Vi6*td0 + Vi7*td1 + Vi8*td2;

        float loss = ux*ux + uy*uy + uz*uz + px*px + py*py + pz*pz;
        term = loss * tweight;
    }

    // block reduction (2 waves)
    float v = term;
    #pragma unroll
    for (int off = 32; off; off >>= 1) v += __shfl_down(v, off, 64);
    if ((tid & 63) == 0) wsum[tid >> 6] = v;
    __syncthreads();
    if (tid == 0)
        partial[b] = (wsum[0] + wsum[1]) * kw[kidx[b]];
}

__global__ __launch_bounds__(256)
void reduce_kernel(const float* __restrict__ partial, float* __restrict__ out, int n) {
    __shared__ float ws[4];
    int tid = threadIdx.x;
    float v = 0.0f;
    for (int i = tid; i < n; i += 256) v += partial[i];
    #pragma unroll
    for (int off = 32; off; off >>= 1) v += __shfl_down(v, off, 64);
    if ((tid & 63) == 0) ws[tid >> 6] = v;
    __syncthreads();
    if (tid == 0)
        out[0] = (ws[0] + ws[1] + ws[2] + ws[3]) * (1.0f / (127.0f * 8192.0f));
}

extern "C" void kernel_launch(void* const* d_in, const int* in_sizes, int n_in,
                              void* d_out, int out_size, void* d_ws, size_t ws_size,
                              hipStream_t stream) {
    const float* traj = (const float*)d_in[0];
    const int*   k    = (const int*)d_in[1];
    const float* tw   = (const float*)d_in[2];
    const float* kw   = (const float*)d_in[3];
    float* out     = (float*)d_out;
    float* partial = (float*)d_ws;
    const int B = in_sizes[1];  // 8192 trajectories

    kin_kernel<<<B, 128, 0, stream>>>(traj, k, tw, kw, partial);
    reduce_kernel<<<1, 256, 0, stream>>>(partial, out, B);
}

// Round 4
// 96.048 us; speedup vs baseline: 2.8204x; 1.0608x over previous
//
#include <hip/hip_runtime.h>
#include <math.h>

#define DEV __device__ __forceinline__

DEV float fast_rcp(float x) { return __builtin_amdgcn_rcpf(x); }

// Abramowitz-Stegun 4.4.45: |err| <= 6.8e-5 rad on [-1,1].
DEV float fast_acos(float x) {
    float ax = fabsf(x);
    float p = fmaf(ax, -0.0187293f, 0.0742610f);
    p = fmaf(ax, p, -0.2121144f);
    p = fmaf(ax, p, 1.5707288f);
    float r = sqrtf(1.0f - ax) * p;
    return (x < 0.0f) ? (3.14159265358979f - r) : r;
}

// se3 exponential; K^2 = phi phi^T - |phi|^2 I identity avoids matmuls.
DEV void se3_exp(float tau0, float tau1, float tau2,
                 float x, float y, float z,
                 float R[9], float t[3]) {
    float th2 = x*x + y*y + z*z;
    float th  = sqrtf(th2);
    bool small = th < 1e-4f;
    float ts  = small ? 1.0f : th;
    float s   = __sinf(ts);
    float c   = __cosf(ts);
    float inv = fast_rcp(ts);
    float A = small ? (1.0f - th2 * (1.0f/6.0f))      : s * inv;
    float B = small ? (0.5f - th2 * (1.0f/24.0f))     : (1.0f - c) * inv * inv;
    float C = small ? (1.0f/6.0f - th2*(1.0f/120.0f)) : (ts - s) * inv * inv * inv;

    float Bxy = B*x*y, Bxz = B*x*z, Byz = B*y*z;
    R[0] = 1.0f - B*(y*y + z*z);
    R[1] = Bxy - A*z;
    R[2] = Bxz + A*y;
    R[3] = Bxy + A*z;
    R[4] = 1.0f - B*(x*x + z*z);
    R[5] = Byz - A*x;
    R[6] = Bxz - A*y;
    R[7] = Byz + A*x;
    R[8] = 1.0f - B*(x*x + y*y);

    float Cxy = C*x*y, Cxz = C*x*z, Cyz = C*y*z;
    float V0 = 1.0f - C*(y*y + z*z);
    float V1 = Cxy - B*z;
    float V2 = Cxz + B*y;
    float V3 = Cxy + B*z;
    float V4 = 1.0f - C*(x*x + z*z);
    float V5 = Cyz - B*x;
    float V6 = Cxz - B*y;
    float V7 = Cyz + B*x;
    float V8 = 1.0f - C*(x*x + y*y);
    t[0] = V0*tau0 + V1*tau1 + V2*tau2;
    t[1] = V3*tau0 + V4*tau1 + V5*tau2;
    t[2] = V6*tau0 + V7*tau1 + V8*tau2;
}

// fwd = exp(v h) ∘ exp(x):  F.R = Rv Rp,  F.t = Rv tp + tv
// bwd = exp(v h)^-1 ∘ exp(x):  B.R = Rv^T Rp,  B.t = Rv^T (tp - tv)
DEV void make_fwd_bwd(const float Rp[9], const float tp[3],
                      const float Rv[9], const float tv[3],
                      float F[12], float Bw[12]) {
    #pragma unroll
    for (int i = 0; i < 3; i++)
        #pragma unroll
        for (int j = 0; j < 3; j++) {
            F[i*3+j]  = Rv[i*3+0]*Rp[0*3+j] + Rv[i*3+1]*Rp[1*3+j] + Rv[i*3+2]*Rp[2*3+j];
            Bw[i*3+j] = Rv[0*3+i]*Rp[0*3+j] + Rv[1*3+i]*Rp[1*3+j] + Rv[2*3+i]*Rp[2*3+j];
        }
    float d0 = tp[0]-tv[0], d1 = tp[1]-tv[1], d2 = tp[2]-tv[2];
    #pragma unroll
    for (int i = 0; i < 3; i++) {
        F[9+i]  = Rv[i*3+0]*tp[0] + Rv[i*3+1]*tp[1] + Rv[i*3+2]*tp[2] + tv[i];
        Bw[9+i] = Rv[0*3+i]*d0 + Rv[1*3+i]*d1 + Rv[2*3+i]*d2;
    }
}

// delta = F ∘ inv(B); return |se3_log(delta)|^2.
// Clamp guarantees th >= 4.47e-4 -> reference `small` branches statically dead;
// sin(th)=sqrt(1-c^2), cos(th)=c -> no trig needed.
DEV float pair_loss(const float F[12], const float B[12]) {
    float Rd[9];
    #pragma unroll
    for (int i = 0; i < 3; i++)
        #pragma unroll
        for (int j = 0; j < 3; j++)
            Rd[i*3+j] = F[i*3+0]*B[j*3+0] + F[i*3+1]*B[j*3+1] + F[i*3+2]*B[j*3+2];
    float td0 = F[9]  - (Rd[0]*B[9] + Rd[1]*B[10] + Rd[2]*B[11]);
    float td1 = F[10] - (Rd[3]*B[9] + Rd[4]*B[10] + Rd[5]*B[11]);
    float td2 = F[11] - (Rd[6]*B[9] + Rd[7]*B[10] + Rd[8]*B[11]);

    float tr = Rd[0] + Rd[4] + Rd[8];
    float c  = fminf(fmaxf((tr - 1.0f) * 0.5f, -1.0f + 1e-7f), 1.0f - 1e-7f);
    float th = fast_acos(c);
    float sn = sqrtf(fmaxf(1.0f - c*c, 1e-20f));
    float coef = th * fast_rcp(2.0f * sn);
    float px = coef * (Rd[7] - Rd[5]);
    float py = coef * (Rd[2] - Rd[6]);
    float pz = coef * (Rd[3] - Rd[1]);

    float D = (1.0f - th*sn*fast_rcp(2.0f*(1.0f - c))) * fast_rcp(th*th);
    float Dxy = D*px*py, Dxz = D*px*pz, Dyz = D*py*pz;
    float Vi0 = 1.0f - D*(py*py + pz*pz);
    float Vi1 = Dxy + 0.5f*pz;
    float Vi2 = Dxz - 0.5f*py;
    float Vi3 = Dxy - 0.5f*pz;
    float Vi4 = 1.0f - D*(px*px + pz*pz);
    float Vi5 = Dyz + 0.5f*px;
    float Vi6 = Dxz + 0.5f*py;
    float Vi7 = Dyz - 0.5f*px;
    float Vi8 = 1.0f - D*(px*px + py*py);
    float ux = Vi0*td0 + Vi1*td1 + Vi2*td2;
    float uy = Vi3*td0 + Vi4*td1 + Vi5*td2;
    float uz = Vi6*td0 + Vi7*td1 + Vi8*td2;

    return ux*ux + uy*uy + uz*uz + px*px + py*py + pz*pz;
}

// One WAVE per trajectory; lane l owns rows 2l, 2l+1 -> pairs 2l, 2l+1.
// Pair 2l   = fwd(row 2l)   ∘ inv(bwd(row 2l+1))   (all local)
// Pair 2l+1 = fwd(row 2l+1) ∘ inv(bwd(row 2l+2))   (bwd via shfl from lane l+1)
// NO __syncthreads, NO LDS in the hot path. 4 trajectories per 256-thread block.
__global__ __launch_bounds__(256)
void kin_kernel(const float* __restrict__ traj, const int* __restrict__ kidx,
                const float* __restrict__ tw, const float* __restrict__ kw,
                float* __restrict__ partial) {
    const int tid     = threadIdx.x;
    const int lane    = tid & 63;
    const int traj_id = blockIdx.x * 4 + (tid >> 6);

    const float* base = traj + (size_t)traj_id * 1536 + lane * 24;
    float4 a0 = *(const float4*)(base + 0);
    float4 a1 = *(const float4*)(base + 4);
    float4 a2 = *(const float4*)(base + 8);
    float4 b0 = *(const float4*)(base + 12);
    float4 b1 = *(const float4*)(base + 16);
    float4 b2 = *(const float4*)(base + 20);

    // issue the dependent kidx->kw chain early so it hides under compute
    float kwv = kw[kidx[traj_id]];
    float w0  = tw[2*lane];                            // 2*63=126: last valid
    float w1  = (lane < 63) ? tw[2*lane + 1] : 0.0f;

    const float h = 0.05f;   // DT/2
    float Rp[9], tp[3], Rv[9], tv[3];

    // even row
    se3_exp(a0.x,a0.y,a0.z, a0.w,a1.x,a1.y, Rp, tp);
    se3_exp(a1.z*h,a1.w*h,a2.x*h, a2.y*h,a2.z*h,a2.w*h, Rv, tv);
    float FA[12], BA[12];
    make_fwd_bwd(Rp,tp,Rv,tv, FA,BA);

    // ship even-row bwd down one lane; receive bwd of row 2l+2 from lane l+1
    float RB[12];
    #pragma unroll
    for (int i = 0; i < 12; i++) RB[i] = __shfl_down(BA[i], 1, 64);

    // odd row
    se3_exp(b0.x,b0.y,b0.z, b0.w,b1.x,b1.y, Rp, tp);
    se3_exp(b1.z*h,b1.w*h,b2.x*h, b2.y*h,b2.z*h,b2.w*h, Rv, tv);
    float FB[12], BB[12];
    make_fwd_bwd(Rp,tp,Rv,tv, FB,BB);

    float term = pair_loss(FA, BB) * w0;               // pair 2l
    if (lane < 63) term += pair_loss(FB, RB) * w1;     // pair 2l+1 (lane 63: none)

    // per-wave (= per-trajectory) reduction, no barriers
    #pragma unroll
    for (int off = 32; off; off >>= 1) term += __shfl_down(term, off, 64);
    if (lane == 0) partial[traj_id] = term * kwv;
}

__global__ __launch_bounds__(512)
void reduce_kernel(const float4* __restrict__ partial4, float* __restrict__ out,
                   int n4, float scale) {
    __shared__ float ws[8];
    int tid = threadIdx.x;
    float v = 0.0f;
    for (int i = tid; i < n4; i += 512) {
        float4 p = partial4[i];
        v += (p.x + p.y) + (p.z + p.w);
    }
    #pragma unroll
    for (int off = 32; off; off >>= 1) v += __shfl_down(v, off, 64);
    if ((tid & 63) == 0) ws[tid >> 6] = v;
    __syncthreads();
    if (tid == 0) {
        float s = 0.0f;
        #pragma unroll
        for (int i = 0; i < 8; i++) s += ws[i];
        out[0] = s * scale;
    }
}

extern "C" void kernel_launch(void* const* d_in, const int* in_sizes, int n_in,
                              void* d_out, int out_size, void* d_ws, size_t ws_size,
                              hipStream_t stream) {
    const float* traj = (const float*)d_in[0];
    const int*   k    = (const int*)d_in[1];
    const float* tw   = (const float*)d_in[2];
    const float* kw   = (const float*)d_in[3];
    float* out     = (float*)d_out;
    float* partial = (float*)d_ws;
    const int B = in_sizes[1];          // 8192 trajectories

    kin_kernel<<<B / 4, 256, 0, stream>>>(traj, k, tw, kw, partial);
    float scale = 1.0f / (127.0f * (float)B);
    reduce_kernel<<<1, 512, 0, stream>>>((const float4*)partial, out, B / 4, scale);
}